// Round 1
// baseline (392.720 us; speedup 1.0000x reference)
//
#include <hip/hip_runtime.h>
#include <hip/hip_bf16.h>

#define NN 200000
#define D 128
#define P 4096
#define R 4
#define T 3
#define K 16

__device__ __forceinline__ float bf2f(unsigned int u) {
    union { unsigned int i; float f; } c;
    c.i = u << 16;
    return c.f;
}
__device__ __forceinline__ unsigned short f2bf(float x) {  // RNE
    union { float f; unsigned int i; } c; c.f = x;
    unsigned int r = c.i + 0x7FFFu + ((c.i >> 16) & 1u);
    return (unsigned short)(r >> 16);
}
__device__ __forceinline__ float ldE(const void* p, size_t i, int f32) {
    return f32 ? ((const float*)p)[i] : bf2f(((const unsigned short*)p)[i]);
}
__device__ __forceinline__ void ld8(const void* p, size_t off, int f32, float* o) {
    if (f32) {
        const float* q = (const float*)p + off;
        float4 a = *(const float4*)q;
        float4 b = *(const float4*)(q + 4);
        o[0]=a.x; o[1]=a.y; o[2]=a.z; o[3]=a.w;
        o[4]=b.x; o[5]=b.y; o[6]=b.z; o[7]=b.w;
    } else {
        uint4 r = *(const uint4*)((const unsigned short*)p + off);
        o[0]=bf2f(r.x & 0xffffu); o[1]=bf2f(r.x >> 16);
        o[2]=bf2f(r.y & 0xffffu); o[3]=bf2f(r.y >> 16);
        o[4]=bf2f(r.z & 0xffffu); o[5]=bf2f(r.z >> 16);
        o[6]=bf2f(r.w & 0xffffu); o[7]=bf2f(r.w >> 16);
    }
}

// Prep kernel: per-block dtype detection + v_t/u_t precompute. Grid = T blocks x 128.
__global__ void prep_kernel(const unsigned short* __restrict__ emb_u,
                            const void* __restrict__ W_phi,
                            const void* __restrict__ W_zeta,
                            int* __restrict__ gflag,
                            float* __restrict__ ws_v, float* __restrict__ ws_u) {
    __shared__ int sbad[2];
    const int tid = threadIdx.x;          // 0..127
    const int t   = blockIdx.x;           // 0..T-1
    // dtype sniff: even-index ushorts of bf16(N(0,1)) have small exponents;
    // of fp32 they are random mantissa bits -> uniform exponents. (validated r2-r5)
    int bad = 0;
    #pragma unroll
    for (int i = 0; i < 4; ++i) {
        unsigned short u = emb_u[(size_t)(blockIdx.x * 512 + tid * 4 + i) * 2 * 97];
        unsigned int e = (u >> 7) & 0xFFu;
        if (e >= 147u) bad = 1;
    }
    int anyb = __any(bad) ? 1 : 0;
    if ((tid & 63) == 0) sbad[tid >> 6] = anyb;
    __syncthreads();
    const int f32 = sbad[0] | sbad[1];
    if (t == 0 && tid == 0) *gflag = f32;

    const int d = tid;
    const size_t rb = (size_t)(t * D + d) * D;
    float av = 0.f, au = 0.f;
    for (int e = 0; e < D; e += 8) {
        float w[8], zn[8], zs[8];
        ld8(W_phi, rb + e, f32, w);
        ld8(W_zeta, e, f32, zn);
        ld8(W_zeta, D + e, f32, zs);
        #pragma unroll
        for (int q = 0; q < 8; ++q) { av += w[q] * zn[q]; au += w[q] * zs[q]; }
    }
    ws_v[t * D + d] = av;
    ws_u[t * D + d] = au;
}

// Fused kernel v2: block = 1 pair x 8 waves; wave = (side, r). Each wave gathers
// its 16 neighbor rows ONCE (issued before the LDS-fill barrier so the random
// loads are in flight during barrier + e_s), then a single score/softmax/agg
// pass. 4x the wave count of v1 -> latency hiding via TLP instead of per-wave
// prefetch pipelining.
__global__ __launch_bounds__(512, 8) void fused_all(
    const void* __restrict__ emb,               // (N,D)
    const int* __restrict__ pairs,              // (P,2)
    const int* __restrict__ types,              // (N,)
    const int* __restrict__ nbr,                // (P,2,R,K)
    const void* __restrict__ dlt,               // (P,2,R,K)
    const void* __restrict__ W_bw,              // (R,D,D)
    const void* __restrict__ W_bb,              // (R,D)
    const float* __restrict__ ws_v,             // (T,D) fp32
    const float* __restrict__ ws_u,             // (T,D) fp32
    const int* __restrict__ flag,
    void* __restrict__ out)                     // (P,D)
{
    __shared__ __align__(16) float vsh[T * D];
    __shared__ __align__(16) float ush[T * D];
    __shared__ __align__(16) float gsh[2][R][D];   // [s][r][d]      4 KB
    __shared__ __align__(16) float gsum[R][D];     // sum over s     2 KB
    __shared__ __align__(16) float ysh[R][D];      // per-r y        2 KB

    const int f32  = *flag;
    const int tid  = threadIdx.x;
    const int wv   = tid >> 6;                  // 0..7
    const int l    = tid & 63;
    const int s    = wv >> 2;                   // side
    const int r    = wv & 3;                    // relation
    const int p    = blockIdx.x;
    const int rsub = l >> 4;                    // quarter-wave
    const int ch   = l & 15;                    // 16B (8-elem) chunk within a row
    const int base = p * 2 * R * K + s * R * K + r * K;   // flat (p,s,r,0)

    // Per-lane row ownership: lane l covers k = l&15 of this wave's (s,r).
    const int k   = l & 15;
    const int nb  = nbr[base + k];
    const float dtv = ldE(dlt, (size_t)(base + k), f32);
    const int ns  = pairs[p * 2 + s];

    // Issue the 16-row gather immediately (rows i*4+rsub, chunk ch).
    int snb[4];
    #pragma unroll
    for (int i = 0; i < 4; ++i) snb[i] = __shfl(nb, i * 4 + rsub, 64);

    const unsigned short* eu = (const unsigned short*)emb;
    uint4 cur[4];
    float rv[4][8];
    if (!f32) {
        #pragma unroll
        for (int i = 0; i < 4; ++i)
            cur[i] = *(const uint4*)(eu + (size_t)snb[i] * D + ch * 8);
    } else {
        #pragma unroll
        for (int i = 0; i < 4; ++i) ld8(emb, (size_t)snb[i] * D + ch * 8, 1, rv[i]);
    }
    const int tp = types[nb];
    const int ts = types[ns];

    // LDS fill of v/u tables overlaps the in-flight gathers.
    for (int i = tid; i < T * D; i += 512) { vsh[i] = ws_v[i]; ush[i] = ws_u[i]; }
    __syncthreads();

    // Side score e_s = emb[pair_s] . u_{type}: lane covers elems 2l, 2l+1.
    float es;
    {
        float a = ldE(emb, (size_t)ns * D + 2 * l,     f32) * ush[ts * D + 2 * l]
                + ldE(emb, (size_t)ns * D + 2 * l + 1, f32) * ush[ts * D + 2 * l + 1];
        #pragma unroll
        for (int off = 1; off <= 32; off <<= 1) a += __shfl_xor(a, off, 64);
        es = a;
    }

    float sdt[4]; int stp[4];
    #pragma unroll
    for (int i = 0; i < 4; ++i) {
        sdt[i] = __shfl(dtv, i * 4 + rsub, 64);
        stp[i] = __shfl(tp,  i * 4 + rsub, 64);
    }

    // Scores e_n = emb[nbr] . v_{type}, reduced over the 16-lane chunk group.
    float ef[4];
    if (!f32) {
        #pragma unroll
        for (int i = 0; i < 4; ++i) {
            const float* vp = vsh + stp[i] * D + ch * 8;
            float4 v0 = *(const float4*)vp;
            float4 v1 = *(const float4*)(vp + 4);
            float a = 0.f;
            a += bf2f(cur[i].x & 0xffffu) * v0.x + bf2f(cur[i].x >> 16) * v0.y;
            a += bf2f(cur[i].y & 0xffffu) * v0.z + bf2f(cur[i].y >> 16) * v0.w;
            a += bf2f(cur[i].z & 0xffffu) * v1.x + bf2f(cur[i].z >> 16) * v1.y;
            a += bf2f(cur[i].w & 0xffffu) * v1.z + bf2f(cur[i].w >> 16) * v1.w;
            #pragma unroll
            for (int off = 1; off <= 8; off <<= 1) a += __shfl_xor(a, off, 64);
            ef[i] = (a + es) * __expf(-sdt[i]);
        }
    } else {
        #pragma unroll
        for (int i = 0; i < 4; ++i) {
            const float* vp = vsh + stp[i] * D + ch * 8;
            float a = 0.f;
            #pragma unroll
            for (int q = 0; q < 8; ++q) a += rv[i][q] * vp[q];
            #pragma unroll
            for (int off = 1; off <= 8; off <<= 1) a += __shfl_xor(a, off, 64);
            ef[i] = (a + es) * __expf(-sdt[i]);
        }
    }

    // Softmax over the 16 rows of (s,r): across i (regs) and rsub (groups).
    float m = fmaxf(fmaxf(ef[0], ef[1]), fmaxf(ef[2], ef[3]));
    m = fmaxf(m, __shfl_xor(m, 16, 64));
    m = fmaxf(m, __shfl_xor(m, 32, 64));
    float al[4], ssum = 0.f;
    #pragma unroll
    for (int i = 0; i < 4; ++i) { al[i] = __expf(ef[i] - m); ssum += al[i]; }
    ssum += __shfl_xor(ssum, 16, 64);
    ssum += __shfl_xor(ssum, 32, 64);
    float inv = 1.f / ssum;

    // Alpha-weighted sum from the same registers.
    float acc[8] = {0.f,0.f,0.f,0.f,0.f,0.f,0.f,0.f};
    if (!f32) {
        #pragma unroll
        for (int i = 0; i < 4; ++i) {
            float a = al[i] * inv;
            acc[0] += a * bf2f(cur[i].x & 0xffffu); acc[1] += a * bf2f(cur[i].x >> 16);
            acc[2] += a * bf2f(cur[i].y & 0xffffu); acc[3] += a * bf2f(cur[i].y >> 16);
            acc[4] += a * bf2f(cur[i].z & 0xffffu); acc[5] += a * bf2f(cur[i].z >> 16);
            acc[6] += a * bf2f(cur[i].w & 0xffffu); acc[7] += a * bf2f(cur[i].w >> 16);
        }
    } else {
        #pragma unroll
        for (int i = 0; i < 4; ++i) {
            float a = al[i] * inv;
            #pragma unroll
            for (int q = 0; q < 8; ++q) acc[q] += a * rv[i][q];
        }
    }
    #pragma unroll
    for (int q = 0; q < 8; ++q) {
        acc[q] += __shfl_xor(acc[q], 16, 64);
        acc[q] += __shfl_xor(acc[q], 32, 64);
    }
    if (rsub == 0) {
        *(float4*)(&gsh[s][r][ch * 8])     = make_float4(acc[0], acc[1], acc[2], acc[3]);
        *(float4*)(&gsh[s][r][ch * 8 + 4]) = make_float4(acc[4], acc[5], acc[6], acc[7]);
    }
    __syncthreads();

    // gsum[r][d] = gsh[0][r][d] + gsh[1][r][d]; 512 threads = R*D exactly.
    {
        const int r2 = tid >> 7, d2 = tid & 127;
        gsum[r2][d2] = gsh[0][r2][d2] + gsh[1][r2][d2];
    }
    __syncthreads();

    // ---- Beta matvec: wave (s,r) computes y_r[e] for e in [s*64, s*64+64).
    // Lane: e-chunk ch8 = l&7 (8 elems), d-group dgrp = l>>3 (16 d's each).
    // d staggered per group so the 8 broadcast reads hit 8 distinct banks.
    float y[8] = {0.f,0.f,0.f,0.f,0.f,0.f,0.f,0.f};
    const int ch8  = l & 7;
    const int dgrp = l >> 3;
    const unsigned short* Wu = (const unsigned short*)W_bw;
    #pragma unroll 4
    for (int dd = 0; dd < 16; ++dd) {
        const int d = dgrp * 16 + ((dd + 2 * dgrp) & 15);
        const float gd = gsum[r][d];
        const size_t wo = ((size_t)(r * D + d)) * D + s * 64 + ch8 * 8;
        if (!f32) {
            uint4 wr = *(const uint4*)(Wu + wo);
            y[0] += gd * bf2f(wr.x & 0xffffu); y[1] += gd * bf2f(wr.x >> 16);
            y[2] += gd * bf2f(wr.y & 0xffffu); y[3] += gd * bf2f(wr.y >> 16);
            y[4] += gd * bf2f(wr.z & 0xffffu); y[5] += gd * bf2f(wr.z >> 16);
            y[6] += gd * bf2f(wr.w & 0xffffu); y[7] += gd * bf2f(wr.w >> 16);
        } else {
            float wb[8]; ld8(W_bw, wo, 1, wb);
            #pragma unroll
            for (int q = 0; q < 8; ++q) y[q] += gd * wb[q];
        }
    }
    #pragma unroll
    for (int q = 0; q < 8; ++q) {
        y[q] += __shfl_xor(y[q], 8, 64);
        y[q] += __shfl_xor(y[q], 16, 64);
        y[q] += __shfl_xor(y[q], 32, 64);
    }
    if (dgrp == 0) {
        *(float4*)(&ysh[r][s * 64 + ch8 * 8])     = make_float4(y[0], y[1], y[2], y[3]);
        *(float4*)(&ysh[r][s * 64 + ch8 * 8 + 4]) = make_float4(y[4], y[5], y[6], y[7]);
    }
    __syncthreads();

    // ---- Epilogue: wave 0, lanes 0..15 (16 lanes -> 256B store).
    if (wv == 0 && l < 16) {
        const int c = l;
        float bs[8] = {0.f,0.f,0.f,0.f,0.f,0.f,0.f,0.f};
        #pragma unroll
        for (int rr = 0; rr < R; ++rr) {
            float bb[8]; ld8(W_bb, (size_t)rr * D + c * 8, f32, bb);
            #pragma unroll
            for (int q = 0; q < 8; ++q) bs[q] += bb[q];
        }
        float o[8];
        #pragma unroll
        for (int q = 0; q < 8; ++q) {
            const int e = c * 8 + q;
            float x = (ysh[0][e] + ysh[1][e] + ysh[2][e] + ysh[3][e] + 2.f * bs[q]) * 0.125f;
            o[q] = 1.f / (1.f + __expf(-x));
        }
        size_t ob = (size_t)p * D + c * 8;
        if (f32) {
            *(float4*)((float*)out + ob)     = make_float4(o[0], o[1], o[2], o[3]);
            *(float4*)((float*)out + ob + 4) = make_float4(o[4], o[5], o[6], o[7]);
        } else {
            uint4 pk;
            pk.x = (unsigned int)f2bf(o[0]) | ((unsigned int)f2bf(o[1]) << 16);
            pk.y = (unsigned int)f2bf(o[2]) | ((unsigned int)f2bf(o[3]) << 16);
            pk.z = (unsigned int)f2bf(o[4]) | ((unsigned int)f2bf(o[5]) << 16);
            pk.w = (unsigned int)f2bf(o[6]) | ((unsigned int)f2bf(o[7]) << 16);
            *(uint4*)((unsigned short*)out + ob) = pk;
        }
    }
}

extern "C" void kernel_launch(void* const* d_in, const int* in_sizes, int n_in,
                              void* d_out, int out_size, void* d_ws, size_t ws_size,
                              hipStream_t stream) {
    const void* emb    = d_in[0];
    const int*  pairs  = (const int*)d_in[1];
    const int*  types  = (const int*)d_in[2];
    const int*  nbr    = (const int*)d_in[3];
    const void* dlt    = d_in[4];
    const void* W_phi  = d_in[5];
    const void* W_zeta = d_in[6];
    const void* W_bw   = d_in[7];
    const void* W_bb   = d_in[8];

    int*   flag = (int*)d_ws;                        // bytes [0,256)
    float* ws_v = (float*)d_ws + 64;                 // 384 floats
    float* ws_u = ws_v + T * D;                      // 384 floats

    prep_kernel<<<dim3(T), dim3(128), 0, stream>>>((const unsigned short*)emb,
                                                   W_phi, W_zeta, flag, ws_v, ws_u);
    fused_all<<<dim3(P), dim3(512), 0, stream>>>(emb, pairs, types, nbr, dlt,
                                                 W_bw, W_bb, ws_v, ws_u, flag, d_out);
}

// Round 2
// 345.022 us; speedup vs baseline: 1.1382x; 1.1382x over previous
//
#include <hip/hip_runtime.h>
#include <hip/hip_bf16.h>

#define NN 200000
#define D 128
#define P 4096
#define R 4
#define T 3
#define K 16

__device__ __forceinline__ float bf2f(unsigned int u) {
    union { unsigned int i; float f; } c;
    c.i = u << 16;
    return c.f;
}
__device__ __forceinline__ unsigned short f2bf(float x) {  // RNE
    union { float f; unsigned int i; } c; c.f = x;
    unsigned int r = c.i + 0x7FFFu + ((c.i >> 16) & 1u);
    return (unsigned short)(r >> 16);
}
__device__ __forceinline__ float ldE(const void* p, size_t i, int f32) {
    return f32 ? ((const float*)p)[i] : bf2f(((const unsigned short*)p)[i]);
}
__device__ __forceinline__ void ld8(const void* p, size_t off, int f32, float* o) {
    if (f32) {
        const float* q = (const float*)p + off;
        float4 a = *(const float4*)q;
        float4 b = *(const float4*)(q + 4);
        o[0]=a.x; o[1]=a.y; o[2]=a.z; o[3]=a.w;
        o[4]=b.x; o[5]=b.y; o[6]=b.z; o[7]=b.w;
    } else {
        uint4 r = *(const uint4*)((const unsigned short*)p + off);
        o[0]=bf2f(r.x & 0xffffu); o[1]=bf2f(r.x >> 16);
        o[2]=bf2f(r.y & 0xffffu); o[3]=bf2f(r.y >> 16);
        o[4]=bf2f(r.z & 0xffffu); o[5]=bf2f(r.z >> 16);
        o[6]=bf2f(r.w & 0xffffu); o[7]=bf2f(r.w >> 16);
    }
}

// Prep kernel: per-block dtype detection + v_t/u_t precompute. Grid = T blocks x 128.
__global__ void prep_kernel(const unsigned short* __restrict__ emb_u,
                            const void* __restrict__ W_phi,
                            const void* __restrict__ W_zeta,
                            int* __restrict__ gflag,
                            float* __restrict__ ws_v, float* __restrict__ ws_u) {
    __shared__ int sbad[2];
    const int tid = threadIdx.x;          // 0..127
    const int t   = blockIdx.x;           // 0..T-1
    // dtype sniff: even-index ushorts of bf16(N(0,1)) have small exponents;
    // of fp32 they are random mantissa bits -> uniform exponents. (validated r2-r5)
    int bad = 0;
    #pragma unroll
    for (int i = 0; i < 4; ++i) {
        unsigned short u = emb_u[(size_t)(blockIdx.x * 512 + tid * 4 + i) * 2 * 97];
        unsigned int e = (u >> 7) & 0xFFu;
        if (e >= 147u) bad = 1;
    }
    int anyb = __any(bad) ? 1 : 0;
    if ((tid & 63) == 0) sbad[tid >> 6] = anyb;
    __syncthreads();
    const int f32 = sbad[0] | sbad[1];
    if (t == 0 && tid == 0) *gflag = f32;

    const int d = tid;
    const size_t rb = (size_t)(t * D + d) * D;
    float av = 0.f, au = 0.f;
    for (int e = 0; e < D; e += 8) {
        float w[8], zn[8], zs[8];
        ld8(W_phi, rb + e, f32, w);
        ld8(W_zeta, e, f32, zn);
        ld8(W_zeta, D + e, f32, zs);
        #pragma unroll
        for (int q = 0; q < 8; ++q) { av += w[q] * zn[q]; au += w[q] * zs[q]; }
    }
    ws_v[t * D + d] = av;
    ws_u[t * D + d] = au;
}

// Fused kernel v3: block = 1 pair x 8 waves; wave = (side, r). Each wave gathers
// its 16 neighbor rows ONCE (issued before the LDS-fill barrier so the random
// loads are in flight during barrier + e_s). v3 fixes v2's register spill:
// fp32 fallback RELOADS rows after softmax instead of holding rv[4][8] live,
// so both paths fit the 64-VGPR budget that 8 waves/SIMD requires.
__global__ __launch_bounds__(512, 8) void fused_all(
    const void* __restrict__ emb,               // (N,D)
    const int* __restrict__ pairs,              // (P,2)
    const int* __restrict__ types,              // (N,)
    const int* __restrict__ nbr,                // (P,2,R,K)
    const void* __restrict__ dlt,               // (P,2,R,K)
    const void* __restrict__ W_bw,              // (R,D,D)
    const void* __restrict__ W_bb,              // (R,D)
    const float* __restrict__ ws_v,             // (T,D) fp32
    const float* __restrict__ ws_u,             // (T,D) fp32
    const int* __restrict__ flag,
    void* __restrict__ out)                     // (P,D)
{
    __shared__ __align__(16) float vsh[T * D];
    __shared__ __align__(16) float ush[T * D];
    __shared__ __align__(16) float gsh[2][R][D];   // [s][r][d]      4 KB
    __shared__ __align__(16) float gsum[R][D];     // sum over s     2 KB
    __shared__ __align__(16) float ysh[R][D];      // per-r y        2 KB

    const int f32  = *flag;
    const int tid  = threadIdx.x;
    const int wv   = tid >> 6;                  // 0..7
    const int l    = tid & 63;
    const int s    = wv >> 2;                   // side
    const int r    = wv & 3;                    // relation
    const int p    = blockIdx.x;
    const int rsub = l >> 4;                    // quarter-wave
    const int ch   = l & 15;                    // 16B (8-elem) chunk within a row
    const int base = p * 2 * R * K + s * R * K + r * K;   // flat (p,s,r,0)

    // Per-lane row ownership: lane l covers k = l&15 of this wave's (s,r).
    const int k   = l & 15;
    const int nb  = nbr[base + k];
    const float dtv = ldE(dlt, (size_t)(base + k), f32);
    const int ns  = pairs[p * 2 + s];

    // Row-gather addressing: lane handles rows i*4+rsub, chunk ch.
    int snb[4];
    #pragma unroll
    for (int i = 0; i < 4; ++i) snb[i] = __shfl(nb, i * 4 + rsub, 64);

    const unsigned short* eu = (const unsigned short*)emb;
    uint4 cur[4];
    if (!f32) {
        // Issue all 4 gathers immediately; they fly during barrier + e_s.
        #pragma unroll
        for (int i = 0; i < 4; ++i)
            cur[i] = *(const uint4*)(eu + (size_t)snb[i] * D + ch * 8);
    }
    const int tp = types[nb];
    const int ts = types[ns];

    // e_s side-row elements hoisted above the barrier too (packed load).
    float ee0, ee1;
    if (!f32) {
        unsigned int w2 = *(const unsigned int*)(eu + (size_t)ns * D + 2 * l);
        ee0 = bf2f(w2 & 0xffffu); ee1 = bf2f(w2 >> 16);
    } else {
        float2 f2 = *(const float2*)((const float*)emb + (size_t)ns * D + 2 * l);
        ee0 = f2.x; ee1 = f2.y;
    }

    // LDS fill of v/u tables overlaps the in-flight loads.
    for (int i = tid; i < T * D; i += 512) { vsh[i] = ws_v[i]; ush[i] = ws_u[i]; }
    __syncthreads();

    // Side score e_s = emb[pair_s] . u_{type}: lane covers elems 2l, 2l+1.
    float es;
    {
        float a = ee0 * ush[ts * D + 2 * l] + ee1 * ush[ts * D + 2 * l + 1];
        #pragma unroll
        for (int off = 1; off <= 32; off <<= 1) a += __shfl_xor(a, off, 64);
        es = a;
    }

    float sdt[4]; int stp[4];
    #pragma unroll
    for (int i = 0; i < 4; ++i) {
        sdt[i] = __shfl(dtv, i * 4 + rsub, 64);
        stp[i] = __shfl(tp,  i * 4 + rsub, 64);
    }

    // Scores e_n = emb[nbr] . v_{type}, reduced over the 16-lane chunk group.
    float ef[4];
    if (!f32) {
        #pragma unroll
        for (int i = 0; i < 4; ++i) {
            const float* vp = vsh + stp[i] * D + ch * 8;
            float4 v0 = *(const float4*)vp;
            float4 v1 = *(const float4*)(vp + 4);
            float a = 0.f;
            a += bf2f(cur[i].x & 0xffffu) * v0.x + bf2f(cur[i].x >> 16) * v0.y;
            a += bf2f(cur[i].y & 0xffffu) * v0.z + bf2f(cur[i].y >> 16) * v0.w;
            a += bf2f(cur[i].z & 0xffffu) * v1.x + bf2f(cur[i].z >> 16) * v1.y;
            a += bf2f(cur[i].w & 0xffffu) * v1.z + bf2f(cur[i].w >> 16) * v1.w;
            #pragma unroll
            for (int off = 1; off <= 8; off <<= 1) a += __shfl_xor(a, off, 64);
            ef[i] = (a + es) * __expf(-sdt[i]);
        }
    } else {
        // fp32 fallback: load one row at a time, dot, discard (no rv[4][8]
        // held across the softmax -> no spill). Rows are reloaded below;
        // fp32 emb (102 MB) is L3-resident so the second pass is cheap.
        #pragma unroll
        for (int i = 0; i < 4; ++i) {
            const float* vp = vsh + stp[i] * D + ch * 8;
            float rv[8];
            ld8(emb, (size_t)snb[i] * D + ch * 8, 1, rv);
            float a = 0.f;
            #pragma unroll
            for (int q = 0; q < 8; ++q) a += rv[q] * vp[q];
            #pragma unroll
            for (int off = 1; off <= 8; off <<= 1) a += __shfl_xor(a, off, 64);
            ef[i] = (a + es) * __expf(-sdt[i]);
        }
    }

    // Softmax over the 16 rows of (s,r): across i (regs) and rsub (groups).
    float m = fmaxf(fmaxf(ef[0], ef[1]), fmaxf(ef[2], ef[3]));
    m = fmaxf(m, __shfl_xor(m, 16, 64));
    m = fmaxf(m, __shfl_xor(m, 32, 64));
    float al[4], ssum = 0.f;
    #pragma unroll
    for (int i = 0; i < 4; ++i) { al[i] = __expf(ef[i] - m); ssum += al[i]; }
    ssum += __shfl_xor(ssum, 16, 64);
    ssum += __shfl_xor(ssum, 32, 64);
    float inv = 1.f / ssum;

    // Alpha-weighted sum.
    float acc[8] = {0.f,0.f,0.f,0.f,0.f,0.f,0.f,0.f};
    if (!f32) {
        #pragma unroll
        for (int i = 0; i < 4; ++i) {
            float a = al[i] * inv;
            acc[0] += a * bf2f(cur[i].x & 0xffffu); acc[1] += a * bf2f(cur[i].x >> 16);
            acc[2] += a * bf2f(cur[i].y & 0xffffu); acc[3] += a * bf2f(cur[i].y >> 16);
            acc[4] += a * bf2f(cur[i].z & 0xffffu); acc[5] += a * bf2f(cur[i].z >> 16);
            acc[6] += a * bf2f(cur[i].w & 0xffffu); acc[7] += a * bf2f(cur[i].w >> 16);
        }
    } else {
        #pragma unroll
        for (int i = 0; i < 4; ++i) {
            float a = al[i] * inv;
            float rv[8];
            ld8(emb, (size_t)snb[i] * D + ch * 8, 1, rv);
            #pragma unroll
            for (int q = 0; q < 8; ++q) acc[q] += a * rv[q];
        }
    }
    #pragma unroll
    for (int q = 0; q < 8; ++q) {
        acc[q] += __shfl_xor(acc[q], 16, 64);
        acc[q] += __shfl_xor(acc[q], 32, 64);
    }
    if (rsub == 0) {
        *(float4*)(&gsh[s][r][ch * 8])     = make_float4(acc[0], acc[1], acc[2], acc[3]);
        *(float4*)(&gsh[s][r][ch * 8 + 4]) = make_float4(acc[4], acc[5], acc[6], acc[7]);
    }
    __syncthreads();

    // gsum[r][d] = gsh[0][r][d] + gsh[1][r][d]; 512 threads = R*D exactly.
    {
        const int r2 = tid >> 7, d2 = tid & 127;
        gsum[r2][d2] = gsh[0][r2][d2] + gsh[1][r2][d2];
    }
    __syncthreads();

    // ---- Beta matvec: wave (s,r) computes y_r[e] for e in [s*64, s*64+64).
    // Lane: e-chunk ch8 = l&7 (8 elems), d-group dgrp = l>>3 (16 d's each).
    // d staggered per group so the 8 broadcast reads hit 8 distinct banks.
    float y[8] = {0.f,0.f,0.f,0.f,0.f,0.f,0.f,0.f};
    const int ch8  = l & 7;
    const int dgrp = l >> 3;
    const unsigned short* Wu = (const unsigned short*)W_bw;
    #pragma unroll 4
    for (int dd = 0; dd < 16; ++dd) {
        const int d = dgrp * 16 + ((dd + 2 * dgrp) & 15);
        const float gd = gsum[r][d];
        const size_t wo = ((size_t)(r * D + d)) * D + s * 64 + ch8 * 8;
        if (!f32) {
            uint4 wr = *(const uint4*)(Wu + wo);
            y[0] += gd * bf2f(wr.x & 0xffffu); y[1] += gd * bf2f(wr.x >> 16);
            y[2] += gd * bf2f(wr.y & 0xffffu); y[3] += gd * bf2f(wr.y >> 16);
            y[4] += gd * bf2f(wr.z & 0xffffu); y[5] += gd * bf2f(wr.z >> 16);
            y[6] += gd * bf2f(wr.w & 0xffffu); y[7] += gd * bf2f(wr.w >> 16);
        } else {
            float wb[8]; ld8(W_bw, wo, 1, wb);
            #pragma unroll
            for (int q = 0; q < 8; ++q) y[q] += gd * wb[q];
        }
    }
    #pragma unroll
    for (int q = 0; q < 8; ++q) {
        y[q] += __shfl_xor(y[q], 8, 64);
        y[q] += __shfl_xor(y[q], 16, 64);
        y[q] += __shfl_xor(y[q], 32, 64);
    }
    if (dgrp == 0) {
        *(float4*)(&ysh[r][s * 64 + ch8 * 8])     = make_float4(y[0], y[1], y[2], y[3]);
        *(float4*)(&ysh[r][s * 64 + ch8 * 8 + 4]) = make_float4(y[4], y[5], y[6], y[7]);
    }
    __syncthreads();

    // ---- Epilogue: wave 0, lanes 0..15 (16 lanes -> 256B store).
    if (wv == 0 && l < 16) {
        const int c = l;
        float bs[8] = {0.f,0.f,0.f,0.f,0.f,0.f,0.f,0.f};
        #pragma unroll
        for (int rr = 0; rr < R; ++rr) {
            float bb[8]; ld8(W_bb, (size_t)rr * D + c * 8, f32, bb);
            #pragma unroll
            for (int q = 0; q < 8; ++q) bs[q] += bb[q];
        }
        float o[8];
        #pragma unroll
        for (int q = 0; q < 8; ++q) {
            const int e = c * 8 + q;
            float x = (ysh[0][e] + ysh[1][e] + ysh[2][e] + ysh[3][e] + 2.f * bs[q]) * 0.125f;
            o[q] = 1.f / (1.f + __expf(-x));
        }
        size_t ob = (size_t)p * D + c * 8;
        if (f32) {
            *(float4*)((float*)out + ob)     = make_float4(o[0], o[1], o[2], o[3]);
            *(float4*)((float*)out + ob + 4) = make_float4(o[4], o[5], o[6], o[7]);
        } else {
            uint4 pk;
            pk.x = (unsigned int)f2bf(o[0]) | ((unsigned int)f2bf(o[1]) << 16);
            pk.y = (unsigned int)f2bf(o[2]) | ((unsigned int)f2bf(o[3]) << 16);
            pk.z = (unsigned int)f2bf(o[4]) | ((unsigned int)f2bf(o[5]) << 16);
            pk.w = (unsigned int)f2bf(o[6]) | ((unsigned int)f2bf(o[7]) << 16);
            *(uint4*)((unsigned short*)out + ob) = pk;
        }
    }
}

extern "C" void kernel_launch(void* const* d_in, const int* in_sizes, int n_in,
                              void* d_out, int out_size, void* d_ws, size_t ws_size,
                              hipStream_t stream) {
    const void* emb    = d_in[0];
    const int*  pairs  = (const int*)d_in[1];
    const int*  types  = (const int*)d_in[2];
    const int*  nbr    = (const int*)d_in[3];
    const void* dlt    = d_in[4];
    const void* W_phi  = d_in[5];
    const void* W_zeta = d_in[6];
    const void* W_bw   = d_in[7];
    const void* W_bb   = d_in[8];

    int*   flag = (int*)d_ws;                        // bytes [0,256)
    float* ws_v = (float*)d_ws + 64;                 // 384 floats
    float* ws_u = ws_v + T * D;                      // 384 floats

    prep_kernel<<<dim3(T), dim3(128), 0, stream>>>((const unsigned short*)emb,
                                                   W_phi, W_zeta, flag, ws_v, ws_u);
    fused_all<<<dim3(P), dim3(512), 0, stream>>>(emb, pairs, types, nbr, dlt,
                                                 W_bw, W_bb, ws_v, ws_u, flag, d_out);
}

// Round 3
// 268.275 us; speedup vs baseline: 1.4639x; 1.2861x over previous
//
#include <hip/hip_runtime.h>
#include <hip/hip_bf16.h>

#define NN 200000
#define D 128
#define P 4096
#define R 4
#define T 3
#define K 16

__device__ __forceinline__ float bf2f(unsigned int u) {
    union { unsigned int i; float f; } c;
    c.i = u << 16;
    return c.f;
}
__device__ __forceinline__ unsigned short f2bf(float x) {  // RNE
    union { float f; unsigned int i; } c; c.f = x;
    unsigned int r = c.i + 0x7FFFu + ((c.i >> 16) & 1u);
    return (unsigned short)(r >> 16);
}
__device__ __forceinline__ float ldE(const void* p, size_t i, int f32) {
    return f32 ? ((const float*)p)[i] : bf2f(((const unsigned short*)p)[i]);
}
__device__ __forceinline__ void ld8(const void* p, size_t off, int f32, float* o) {
    if (f32) {
        const float* q = (const float*)p + off;
        float4 a = *(const float4*)q;
        float4 b = *(const float4*)(q + 4);
        o[0]=a.x; o[1]=a.y; o[2]=a.z; o[3]=a.w;
        o[4]=b.x; o[5]=b.y; o[6]=b.z; o[7]=b.w;
    } else {
        uint4 r = *(const uint4*)((const unsigned short*)p + off);
        o[0]=bf2f(r.x & 0xffffu); o[1]=bf2f(r.x >> 16);
        o[2]=bf2f(r.y & 0xffffu); o[3]=bf2f(r.y >> 16);
        o[4]=bf2f(r.z & 0xffffu); o[5]=bf2f(r.z >> 16);
        o[6]=bf2f(r.w & 0xffffu); o[7]=bf2f(r.w >> 16);
    }
}

// Prep kernel: per-block dtype detection + v_t/u_t precompute. Grid = T blocks x 128.
__global__ void prep_kernel(const unsigned short* __restrict__ emb_u,
                            const void* __restrict__ W_phi,
                            const void* __restrict__ W_zeta,
                            int* __restrict__ gflag,
                            float* __restrict__ ws_v, float* __restrict__ ws_u) {
    __shared__ int sbad[2];
    const int tid = threadIdx.x;          // 0..127
    const int t   = blockIdx.x;           // 0..T-1
    // dtype sniff: even-index ushorts of bf16(N(0,1)) have small exponents;
    // of fp32 they are random mantissa bits -> uniform exponents. (validated r2-r5)
    int bad = 0;
    #pragma unroll
    for (int i = 0; i < 4; ++i) {
        unsigned short u = emb_u[(size_t)(blockIdx.x * 512 + tid * 4 + i) * 2 * 97];
        unsigned int e = (u >> 7) & 0xFFu;
        if (e >= 147u) bad = 1;
    }
    int anyb = __any(bad) ? 1 : 0;
    if ((tid & 63) == 0) sbad[tid >> 6] = anyb;
    __syncthreads();
    const int f32 = sbad[0] | sbad[1];
    if (t == 0 && tid == 0) *gflag = f32;

    const int d = tid;
    const size_t rb = (size_t)(t * D + d) * D;
    float av = 0.f, au = 0.f;
    for (int e = 0; e < D; e += 8) {
        float w[8], zn[8], zs[8];
        ld8(W_phi, rb + e, f32, w);
        ld8(W_zeta, e, f32, zn);
        ld8(W_zeta, D + e, f32, zs);
        #pragma unroll
        for (int q = 0; q < 8; ++q) { av += w[q] * zn[q]; au += w[q] * zs[q]; }
    }
    ws_v[t * D + d] = av;
    ws_u[t * D + d] = au;
}

// Fused kernel v4: identical structure to v3 (block = 1 pair x 8 waves; wave =
// (side, r); single up-front gather batch per wave). ONE change: launch bounds.
// Empirically (v1 VGPR=52 @ (256,4); v2/v3 VGPR=32 @ (512,8)) this compiler
// treats the 2nd __launch_bounds__ arg as MIN WORKGROUPS PER CU, unclamped:
// (512,8) -> 64 waves/CU assumed -> 32-VGPR cap -> massive scratch spill
// (279-420 MB of WRITE_SIZE). (512,4) -> 32 waves/CU (HW max, same occupancy
// goal) -> 64-VGPR budget -> bf16 path (~50 live regs) fits with no spill.
__global__ __launch_bounds__(512, 4) void fused_all(
    const void* __restrict__ emb,               // (N,D)
    const int* __restrict__ pairs,              // (P,2)
    const int* __restrict__ types,              // (N,)
    const int* __restrict__ nbr,                // (P,2,R,K)
    const void* __restrict__ dlt,               // (P,2,R,K)
    const void* __restrict__ W_bw,              // (R,D,D)
    const void* __restrict__ W_bb,              // (R,D)
    const float* __restrict__ ws_v,             // (T,D) fp32
    const float* __restrict__ ws_u,             // (T,D) fp32
    const int* __restrict__ flag,
    void* __restrict__ out)                     // (P,D)
{
    __shared__ __align__(16) float vsh[T * D];
    __shared__ __align__(16) float ush[T * D];
    __shared__ __align__(16) float gsh[2][R][D];   // [s][r][d]      4 KB
    __shared__ __align__(16) float gsum[R][D];     // sum over s     2 KB
    __shared__ __align__(16) float ysh[R][D];      // per-r y        2 KB

    const int f32  = *flag;
    const int tid  = threadIdx.x;
    const int wv   = tid >> 6;                  // 0..7
    const int l    = tid & 63;
    const int s    = wv >> 2;                   // side
    const int r    = wv & 3;                    // relation
    const int p    = blockIdx.x;
    const int rsub = l >> 4;                    // quarter-wave
    const int ch   = l & 15;                    // 16B (8-elem) chunk within a row
    const int base = p * 2 * R * K + s * R * K + r * K;   // flat (p,s,r,0)

    // Per-lane row ownership: lane l covers k = l&15 of this wave's (s,r).
    const int k   = l & 15;
    const int nb  = nbr[base + k];
    const float dtv = ldE(dlt, (size_t)(base + k), f32);
    const int ns  = pairs[p * 2 + s];

    // Row-gather addressing: lane handles rows i*4+rsub, chunk ch.
    int snb[4];
    #pragma unroll
    for (int i = 0; i < 4; ++i) snb[i] = __shfl(nb, i * 4 + rsub, 64);

    const unsigned short* eu = (const unsigned short*)emb;
    uint4 cur[4];
    if (!f32) {
        // Issue all 4 gathers immediately; they fly during barrier + e_s.
        #pragma unroll
        for (int i = 0; i < 4; ++i)
            cur[i] = *(const uint4*)(eu + (size_t)snb[i] * D + ch * 8);
    }
    const int tp = types[nb];
    const int ts = types[ns];

    // e_s side-row elements hoisted above the barrier too (packed load).
    float ee0, ee1;
    if (!f32) {
        unsigned int w2 = *(const unsigned int*)(eu + (size_t)ns * D + 2 * l);
        ee0 = bf2f(w2 & 0xffffu); ee1 = bf2f(w2 >> 16);
    } else {
        float2 f2 = *(const float2*)((const float*)emb + (size_t)ns * D + 2 * l);
        ee0 = f2.x; ee1 = f2.y;
    }

    // LDS fill of v/u tables overlaps the in-flight loads.
    for (int i = tid; i < T * D; i += 512) { vsh[i] = ws_v[i]; ush[i] = ws_u[i]; }
    __syncthreads();

    // Side score e_s = emb[pair_s] . u_{type}: lane covers elems 2l, 2l+1.
    float es;
    {
        float a = ee0 * ush[ts * D + 2 * l] + ee1 * ush[ts * D + 2 * l + 1];
        #pragma unroll
        for (int off = 1; off <= 32; off <<= 1) a += __shfl_xor(a, off, 64);
        es = a;
    }

    float sdt[4]; int stp[4];
    #pragma unroll
    for (int i = 0; i < 4; ++i) {
        sdt[i] = __shfl(dtv, i * 4 + rsub, 64);
        stp[i] = __shfl(tp,  i * 4 + rsub, 64);
    }

    // Scores e_n = emb[nbr] . v_{type}, reduced over the 16-lane chunk group.
    float ef[4];
    if (!f32) {
        #pragma unroll
        for (int i = 0; i < 4; ++i) {
            const float* vp = vsh + stp[i] * D + ch * 8;
            float4 v0 = *(const float4*)vp;
            float4 v1 = *(const float4*)(vp + 4);
            float a = 0.f;
            a += bf2f(cur[i].x & 0xffffu) * v0.x + bf2f(cur[i].x >> 16) * v0.y;
            a += bf2f(cur[i].y & 0xffffu) * v0.z + bf2f(cur[i].y >> 16) * v0.w;
            a += bf2f(cur[i].z & 0xffffu) * v1.x + bf2f(cur[i].z >> 16) * v1.y;
            a += bf2f(cur[i].w & 0xffffu) * v1.z + bf2f(cur[i].w >> 16) * v1.w;
            #pragma unroll
            for (int off = 1; off <= 8; off <<= 1) a += __shfl_xor(a, off, 64);
            ef[i] = (a + es) * __expf(-sdt[i]);
        }
    } else {
        // fp32 fallback: load one row at a time, dot, discard (no rv[4][8]
        // held across the softmax -> no spill). Rows are reloaded below;
        // fp32 emb (102 MB) is L3-resident so the second pass is cheap.
        #pragma unroll
        for (int i = 0; i < 4; ++i) {
            const float* vp = vsh + stp[i] * D + ch * 8;
            float rv[8];
            ld8(emb, (size_t)snb[i] * D + ch * 8, 1, rv);
            float a = 0.f;
            #pragma unroll
            for (int q = 0; q < 8; ++q) a += rv[q] * vp[q];
            #pragma unroll
            for (int off = 1; off <= 8; off <<= 1) a += __shfl_xor(a, off, 64);
            ef[i] = (a + es) * __expf(-sdt[i]);
        }
    }

    // Softmax over the 16 rows of (s,r): across i (regs) and rsub (groups).
    float m = fmaxf(fmaxf(ef[0], ef[1]), fmaxf(ef[2], ef[3]));
    m = fmaxf(m, __shfl_xor(m, 16, 64));
    m = fmaxf(m, __shfl_xor(m, 32, 64));
    float al[4], ssum = 0.f;
    #pragma unroll
    for (int i = 0; i < 4; ++i) { al[i] = __expf(ef[i] - m); ssum += al[i]; }
    ssum += __shfl_xor(ssum, 16, 64);
    ssum += __shfl_xor(ssum, 32, 64);
    float inv = 1.f / ssum;

    // Alpha-weighted sum.
    float acc[8] = {0.f,0.f,0.f,0.f,0.f,0.f,0.f,0.f};
    if (!f32) {
        #pragma unroll
        for (int i = 0; i < 4; ++i) {
            float a = al[i] * inv;
            acc[0] += a * bf2f(cur[i].x & 0xffffu); acc[1] += a * bf2f(cur[i].x >> 16);
            acc[2] += a * bf2f(cur[i].y & 0xffffu); acc[3] += a * bf2f(cur[i].y >> 16);
            acc[4] += a * bf2f(cur[i].z & 0xffffu); acc[5] += a * bf2f(cur[i].z >> 16);
            acc[6] += a * bf2f(cur[i].w & 0xffffu); acc[7] += a * bf2f(cur[i].w >> 16);
        }
    } else {
        #pragma unroll
        for (int i = 0; i < 4; ++i) {
            float a = al[i] * inv;
            float rv[8];
            ld8(emb, (size_t)snb[i] * D + ch * 8, 1, rv);
            #pragma unroll
            for (int q = 0; q < 8; ++q) acc[q] += a * rv[q];
        }
    }
    #pragma unroll
    for (int q = 0; q < 8; ++q) {
        acc[q] += __shfl_xor(acc[q], 16, 64);
        acc[q] += __shfl_xor(acc[q], 32, 64);
    }
    if (rsub == 0) {
        *(float4*)(&gsh[s][r][ch * 8])     = make_float4(acc[0], acc[1], acc[2], acc[3]);
        *(float4*)(&gsh[s][r][ch * 8 + 4]) = make_float4(acc[4], acc[5], acc[6], acc[7]);
    }
    __syncthreads();

    // gsum[r][d] = gsh[0][r][d] + gsh[1][r][d]; 512 threads = R*D exactly.
    {
        const int r2 = tid >> 7, d2 = tid & 127;
        gsum[r2][d2] = gsh[0][r2][d2] + gsh[1][r2][d2];
    }
    __syncthreads();

    // ---- Beta matvec: wave (s,r) computes y_r[e] for e in [s*64, s*64+64).
    // Lane: e-chunk ch8 = l&7 (8 elems), d-group dgrp = l>>3 (16 d's each).
    // d staggered per group so the 8 broadcast reads hit 8 distinct banks.
    float y[8] = {0.f,0.f,0.f,0.f,0.f,0.f,0.f,0.f};
    const int ch8  = l & 7;
    const int dgrp = l >> 3;
    const unsigned short* Wu = (const unsigned short*)W_bw;
    #pragma unroll 4
    for (int dd = 0; dd < 16; ++dd) {
        const int d = dgrp * 16 + ((dd + 2 * dgrp) & 15);
        const float gd = gsum[r][d];
        const size_t wo = ((size_t)(r * D + d)) * D + s * 64 + ch8 * 8;
        if (!f32) {
            uint4 wr = *(const uint4*)(Wu + wo);
            y[0] += gd * bf2f(wr.x & 0xffffu); y[1] += gd * bf2f(wr.x >> 16);
            y[2] += gd * bf2f(wr.y & 0xffffu); y[3] += gd * bf2f(wr.y >> 16);
            y[4] += gd * bf2f(wr.z & 0xffffu); y[5] += gd * bf2f(wr.z >> 16);
            y[6] += gd * bf2f(wr.w & 0xffffu); y[7] += gd * bf2f(wr.w >> 16);
        } else {
            float wb[8]; ld8(W_bw, wo, 1, wb);
            #pragma unroll
            for (int q = 0; q < 8; ++q) y[q] += gd * wb[q];
        }
    }
    #pragma unroll
    for (int q = 0; q < 8; ++q) {
        y[q] += __shfl_xor(y[q], 8, 64);
        y[q] += __shfl_xor(y[q], 16, 64);
        y[q] += __shfl_xor(y[q], 32, 64);
    }
    if (dgrp == 0) {
        *(float4*)(&ysh[r][s * 64 + ch8 * 8])     = make_float4(y[0], y[1], y[2], y[3]);
        *(float4*)(&ysh[r][s * 64 + ch8 * 8 + 4]) = make_float4(y[4], y[5], y[6], y[7]);
    }
    __syncthreads();

    // ---- Epilogue: wave 0, lanes 0..15 (16 lanes -> 256B store).
    if (wv == 0 && l < 16) {
        const int c = l;
        float bs[8] = {0.f,0.f,0.f,0.f,0.f,0.f,0.f,0.f};
        #pragma unroll
        for (int rr = 0; rr < R; ++rr) {
            float bb[8]; ld8(W_bb, (size_t)rr * D + c * 8, f32, bb);
            #pragma unroll
            for (int q = 0; q < 8; ++q) bs[q] += bb[q];
        }
        float o[8];
        #pragma unroll
        for (int q = 0; q < 8; ++q) {
            const int e = c * 8 + q;
            float x = (ysh[0][e] + ysh[1][e] + ysh[2][e] + ysh[3][e] + 2.f * bs[q]) * 0.125f;
            o[q] = 1.f / (1.f + __expf(-x));
        }
        size_t ob = (size_t)p * D + c * 8;
        if (f32) {
            *(float4*)((float*)out + ob)     = make_float4(o[0], o[1], o[2], o[3]);
            *(float4*)((float*)out + ob + 4) = make_float4(o[4], o[5], o[6], o[7]);
        } else {
            uint4 pk;
            pk.x = (unsigned int)f2bf(o[0]) | ((unsigned int)f2bf(o[1]) << 16);
            pk.y = (unsigned int)f2bf(o[2]) | ((unsigned int)f2bf(o[3]) << 16);
            pk.z = (unsigned int)f2bf(o[4]) | ((unsigned int)f2bf(o[5]) << 16);
            pk.w = (unsigned int)f2bf(o[6]) | ((unsigned int)f2bf(o[7]) << 16);
            *(uint4*)((unsigned short*)out + ob) = pk;
        }
    }
}

extern "C" void kernel_launch(void* const* d_in, const int* in_sizes, int n_in,
                              void* d_out, int out_size, void* d_ws, size_t ws_size,
                              hipStream_t stream) {
    const void* emb    = d_in[0];
    const int*  pairs  = (const int*)d_in[1];
    const int*  types  = (const int*)d_in[2];
    const int*  nbr    = (const int*)d_in[3];
    const void* dlt    = d_in[4];
    const void* W_phi  = d_in[5];
    const void* W_zeta = d_in[6];
    const void* W_bw   = d_in[7];
    const void* W_bb   = d_in[8];

    int*   flag = (int*)d_ws;                        // bytes [0,256)
    float* ws_v = (float*)d_ws + 64;                 // 384 floats
    float* ws_u = ws_v + T * D;                      // 384 floats

    prep_kernel<<<dim3(T), dim3(128), 0, stream>>>((const unsigned short*)emb,
                                                   W_phi, W_zeta, flag, ws_v, ws_u);
    fused_all<<<dim3(P), dim3(512), 0, stream>>>(emb, pairs, types, nbr, dlt,
                                                 W_bw, W_bb, ws_v, ws_u, flag, d_out);
}